// Round 5
// baseline (5126.268 us; speedup 1.0000x reference)
//
#include <hip/hip_runtime.h>
#include <hip/hip_bf16.h>

// Spatial_Weighting: per (b,t): feats = K1 K1^T + K2 K2^T (784x784, K=768 each),
// W = (feats>0.2)?1:1e-5, normalized-Laplacian Fiedler vector, bipartition softmax.
// KEY INSIGHT (R4): reference "np" mask comes from FLOAT32 einsum (numpy SSE
// 4-lane single-accumulator, no FMA); downstream solve is f64. We emulate the
// f32 einsum bit-exactly for the mask, then run the f64 restarted Lanczos.

constexpr int NB = 32;        // B*T batches
constexpr int N  = 784;       // nodes
constexpr int H  = 12, Dd = 64;
constexpr int NW = 13;        // u64 words per row (832 bits, 784 used)
constexpr int MMAX = 384;     // Lanczos basis cap per cycle
constexpr double WA = 1e-5;          // base weight
constexpr double WB = 1.0 - 1e-5;    // extra weight on masked entries
constexpr double TOL = 1e-10;        // Ritz residual tol (angle err ~1e-7)
constexpr int BUDGET = 1536;         // total matvecs per batch across restarts

// ---- Kernel 1: numpy-f32-einsum-emulating Gram + threshold -> bitmask ----
// numpy einsum f32 contig dot: single __m128 accumulator, 8 elems/iter
// (two mul+add into same acc), per-lane sequential in c-block order,
// horizontal sum (s0+s2)+(s1+s3). ein(k1)+ein(k2) as one final f32 add.
__global__ __launch_bounds__(256)
void k_gram_np(const float* __restrict__ k1, const float* __restrict__ k2,
               unsigned long long* __restrict__ mask) {
  const int tx = threadIdx.x & 15, ty = threadIdx.x >> 4;
  const int bx = blockIdx.x, by = blockIdx.y, b = blockIdx.z;
  const int n0 = by * 64, m0 = bx * 64;

  __shared__ float As[64][17];
  __shared__ float Bs[64][17];
  __shared__ unsigned int mw[64][2];

  float e01[2][4][4];

  const float* keys[2] = {k1 + (size_t)b * H * N * Dd, k2 + (size_t)b * H * N * Dd};

#pragma unroll
  for (int ki = 0; ki < 2; ++ki) {
    // 4 SSE lanes per (i,j) pair: acc[i][j][L], L = c % 4
    float acc[4][4][4];
#pragma unroll
    for (int i = 0; i < 4; ++i)
#pragma unroll
      for (int j = 0; j < 4; ++j)
#pragma unroll
        for (int L = 0; L < 4; ++L) acc[i][j][L] = 0.0f;

    const float* K = keys[ki];
    for (int h = 0; h < H; ++h) {
      const float* Kh = K + (size_t)h * N * Dd;
      for (int dc = 0; dc < 4; ++dc) {   // 4 chunks of 16 along D
        const int lr = threadIdx.x >> 2;
        const int lc = (threadIdx.x & 3) * 4;
        {
          int gr = n0 + lr; int grc = gr < N ? gr : N - 1;
          const float4 a4 = *(const float4*)(Kh + (size_t)grc * Dd + dc * 16 + lc);
          As[lr][lc + 0] = a4.x; As[lr][lc + 1] = a4.y; As[lr][lc + 2] = a4.z; As[lr][lc + 3] = a4.w;
          int gr2 = m0 + lr; int grc2 = gr2 < N ? gr2 : N - 1;
          const float4 b4 = *(const float4*)(Kh + (size_t)grc2 * Dd + dc * 16 + lc);
          Bs[lr][lc + 0] = b4.x; Bs[lr][lc + 1] = b4.y; Bs[lr][lc + 2] = b4.z; Bs[lr][lc + 3] = b4.w;
        }
        __syncthreads();
        // 4 SSE blocks of 4 within this 16-wide chunk, increasing c order.
        // EXACT numpy op order per lane: acc = fadd(acc, fmul(a,b)), no FMA.
#pragma unroll
        for (int kb = 0; kb < 4; ++kb) {
#pragma unroll
          for (int i = 0; i < 4; ++i) {
#pragma unroll
            for (int j = 0; j < 4; ++j) {
#pragma unroll
              for (int L = 0; L < 4; ++L) {
                acc[i][j][L] = __fadd_rn(acc[i][j][L],
                    __fmul_rn(As[ty * 4 + i][kb * 4 + L], Bs[tx * 4 + j][kb * 4 + L]));
              }
            }
          }
        }
        __syncthreads();
      }
    }
    // EINSUM_SUM_SSE: (s0+s2) + (s1+s3)
#pragma unroll
    for (int i = 0; i < 4; ++i)
#pragma unroll
      for (int j = 0; j < 4; ++j)
        e01[ki][i][j] = __fadd_rn(__fadd_rn(acc[i][j][0], acc[i][j][2]),
                                  __fadd_rn(acc[i][j][1], acc[i][j][3]));
  }

  if (threadIdx.x < 128) ((unsigned int*)mw)[threadIdx.x] = 0u;
  __syncthreads();
#pragma unroll
  for (int i = 0; i < 4; ++i) {
    unsigned int nib = 0;
#pragma unroll
    for (int j = 0; j < 4; ++j) {
      int m = m0 + tx * 4 + j;
      float feats = __fadd_rn(e01[0][i][j], e01[1][i][j]);  // ein1 + ein2 in f32
      if (m < N && feats > 0.2f) nib |= (1u << j);
    }
    atomicOr(&mw[ty * 4 + i][tx >> 3], nib << ((tx & 7) * 4));
  }
  __syncthreads();
  if (threadIdx.x < 64) {
    int n = n0 + threadIdx.x;
    if (n < N) {
      unsigned long long w =
          ((unsigned long long)mw[threadIdx.x][1] << 32) | (unsigned long long)mw[threadIdx.x][0];
      mask[((size_t)b * NW + bx) * N + n] = w;
    }
  }
}

// ---------------- Kernel 2: degrees, invsqrt(d), u0 = sqrt(d)/||sqrt(d)|| ----
__global__ __launch_bounds__(256)
void k_stats(const unsigned long long* __restrict__ mask,
             double* __restrict__ q, double* __restrict__ u0) {
  const int b = blockIdx.x, tid = threadIdx.x;
  __shared__ double red[4];
  double loc = 0.0;
  for (int n = tid; n < N; n += 256) {
    int c = 0;
    for (int w = 0; w < NW; ++w) c += __popcll(mask[((size_t)b * NW + w) * N + n]);
    double d = (double)c * WB + (double)N * WA;
    q[(size_t)b * N + n] = 1.0 / sqrt(d);
    u0[(size_t)b * N + n] = sqrt(d);
    loc += d;
  }
#pragma unroll
  for (int o = 32; o; o >>= 1) loc += __shfl_down(loc, o);
  if ((tid & 63) == 0) red[tid >> 6] = loc;
  __syncthreads();
  if (tid == 0) red[0] = 1.0 / sqrt(red[0] + red[1] + red[2] + red[3]);
  __syncthreads();
  double inv = red[0];
  for (int n = tid; n < N; n += 256) u0[(size_t)b * N + n] *= inv;
}

// ---------------- helpers ----------------
__device__ __forceinline__ double rnd01(unsigned long long x) {
  x += 0x9E3779B97F4A7C15ull;
  x = (x ^ (x >> 30)) * 0xBF58476D1CE4E5B9ull;
  x = (x ^ (x >> 27)) * 0x94D049BB133111EBull;
  x ^= x >> 31;
  return (double)(x >> 11) * (1.0 / 9007199254740992.0) - 0.5;
}

__device__ __forceinline__ double bsum(double v, double* red) {
  const int tid = threadIdx.x;
  __syncthreads();
#pragma unroll
  for (int o = 32; o; o >>= 1) v += __shfl_down(v, o);
  if ((tid & 63) == 0) red[tid >> 6] = v;
  __syncthreads();
  if (tid < 64) {
    double x = (tid < 16) ? red[tid] : 0.0;
#pragma unroll
    for (int o = 8; o; o >>= 1) x += __shfl_down(x, o);
    if (tid == 0) red[0] = x;
  }
  __syncthreads();
  return red[0];
}

__device__ __forceinline__ double bmax(double v, double* red) {
  const int tid = threadIdx.x;
  __syncthreads();
#pragma unroll
  for (int o = 32; o; o >>= 1) v = fmax(v, __shfl_down(v, o));
  if ((tid & 63) == 0) red[tid >> 6] = v;
  __syncthreads();
  if (tid < 64) {
    double x = (tid < 16) ? red[tid] : -1e300;
#pragma unroll
    for (int o = 8; o; o >>= 1) x = fmax(x, __shfl_down(x, o));
    if (tid == 0) red[0] = x;
  }
  __syncthreads();
  return red[0];
}

// Sturm count: #eigenvalues of T_m below x
__device__ int cntless(const double* al, const double* be, int m, double x) {
  double d = al[0] - x;
  int c = (d < 0.0);
  for (int i = 1; i < m; ++i) {
    double den = d;
    if (fabs(den) < 1e-300) den = (den < 0.0 ? -1e-300 : 1e-300);
    d = al[i] - x - be[i] * be[i] / den;
    c += (d < 0.0);
  }
  return c;
}

// CGS2 full reorth of ww (LDS, length N) against V[0..k] (global)
__device__ void cgs2(double* ww, const double* Vb, int k, double* cd, double* red) {
  const int tid = threadIdx.x, wv = tid >> 6, lane = tid & 63;
  for (int round = 0; round < 2; ++round) {
    __syncthreads();
    for (int j = wv; j <= k; j += 16) {
      const double* Vj = Vb + (size_t)j * N;
      double p = 0.0;
      for (int c = lane; c < N; c += 64) p += ww[c] * Vj[c];
#pragma unroll
      for (int o = 32; o; o >>= 1) p += __shfl_down(p, o);
      if (lane == 0) cd[j] = p;
    }
    __syncthreads();
    const int rr = wv * 49 + lane;   // 16*49 = 784
    if (lane < 49) {
      double acc = ww[rr];
      for (int j = 0; j <= k; ++j) acc -= cd[j] * Vb[(size_t)j * N + rr];
      ww[rr] = acc;
    }
    __syncthreads();
  }
}

// ---------------- Kernel 3: persistent per-batch restarted Lanczos ---------
__global__ __launch_bounds__(1024)
void k_lanczos(const unsigned long long* __restrict__ mask,
               const double* __restrict__ qg, const double* __restrict__ u0g,
               double* __restrict__ V, float* __restrict__ out, int mcap, int wsMB) {
  const int b = blockIdx.x;
  const int tid = threadIdx.x;
  const int lane = tid & 63, wv = tid >> 6;
  const int r = tid;  // row (active when r < N)

  __shared__ double zs[N], ww[N], vp[N], u0s[N], qs[N];
  __shared__ double tbl[416 * 4];
  __shared__ double al[MMAX + 1], be[MMAX + 2], yv[MMAX + 1];
  __shared__ double t1[MMAX + 1], t2[MMAX + 1], t3[MMAX + 1], t4[MMAX + 1];
  __shared__ double red[16];
  __shared__ double sc[8];

  const unsigned long long* mrow = mask + (size_t)b * NW * N;
  double* Vb = V + (size_t)b * mcap * N;

  if (r < N) {
    qs[r] = qg[(size_t)b * N + r];
    u0s[r] = u0g[(size_t)b * N + r];
    zs[r] = rnd01((unsigned long long)(b * 100003 + r));
  }
  for (int g = tid + 392 * 4; g < 416 * 4; g += 1024) tbl[g] = 0.0;  // pad groups
  __syncthreads();

  // project out exact top eigvec u0, normalize
  double c0 = bsum((r < N) ? zs[r] * u0s[r] : 0.0, red);
  if (r < N) zs[r] -= c0 * u0s[r];
  double nr = sqrt(bsum((r < N) ? zs[r] * zs[r] : 0.0, red));
  if (r < N) zs[r] /= nr;

  bool conv = false;
  int totm = 0, mfin = 0;
  double lastResid = 1e30;

  for (int cyc = 0; cyc < 16; ++cyc) {
    if (r < N) { Vb[r] = zs[r]; vp[r] = 0.0; }
    if (tid == 0) be[0] = 0.0;
    __syncthreads();

    int m = 0;
    for (int k = 0; k < mcap; ++k) {
      __syncthreads();
      if (r < N) ww[r] = qs[r] * zs[r];
      double s1 = bsum((r < N) ? ww[r] : 0.0, red);
      for (int g = tid; g < 392; g += 1024) {
        double a0 = ww[2 * g], a1 = ww[2 * g + 1];
        tbl[4 * g + 0] = 0.0; tbl[4 * g + 1] = a0; tbl[4 * g + 2] = a1; tbl[4 * g + 3] = a0 + a1;
      }
      __syncthreads();
      if (r < N) {
        unsigned long long wbits[NW];
#pragma unroll
        for (int w = 0; w < NW; ++w) wbits[w] = mrow[(size_t)w * N + r];
        double acc0 = 0.0, acc1 = 0.0;
#pragma unroll
        for (int w = 0; w < NW; ++w) {
          unsigned long long bits = wbits[w];
          const double* tb = &tbl[w * 128];
#pragma unroll
          for (int p = 0; p < 32; p += 2) {
            acc0 += tb[p * 4 + (int)(bits & 3ull)];
            acc1 += tb[p * 4 + 4 + (int)((bits >> 2) & 3ull)];
            bits >>= 4;
          }
        }
        ww[r] = qs[r] * (WB * (acc0 + acc1) + WA * s1);
      }
      ++totm;
      double alpha = bsum((r < N) ? ww[r] * zs[r] : 0.0, red);
      if (tid == 0) al[k] = alpha;
      double bk = be[k];
      if (r < N) ww[r] -= alpha * zs[r] + bk * vp[r];
      double cu = bsum((r < N) ? ww[r] * u0s[r] : 0.0, red);
      if (r < N) ww[r] -= cu * u0s[r];

      m = k + 1;
      const bool doRe = ((m & 15) == 0) || (m == mcap);
      if (doRe) cgs2(ww, Vb, k, yv, red);

      double bnew = sqrt(bsum((r < N) ? ww[r] * ww[r] : 0.0, red));
      if (tid == 0) be[m] = bnew;
      __syncthreads();

      const bool doCheck = (((m & 15) == 0) && m >= 32) || (m == mcap);
      if (doCheck) {
        double gmax = bmax((tid < m) ? al[tid] + (tid > 0 ? be[tid] : 0.0) +
                                           (tid < m - 1 ? be[tid + 1] : 0.0)
                                     : -1e300, red);
        double dmax = bmax((tid < m) ? al[tid] : -1e300, red);
        if (tid < 64) {
          double lo = dmax, hi = gmax + 1e-9;
          for (int round = 0; round < 4; ++round) {
            double xl = lo + (hi - lo) * (double)(lane + 1) * (1.0 / 65.0);
            int c = cntless(al, be, m, xl);
            unsigned long long mk = __ballot(c >= m);
            int fl = (mk == 0ull) ? 64 : (__ffsll(mk) - 1);
            double nlo = lo + (hi - lo) * (double)fl * (1.0 / 65.0);
            double nhi = (fl < 64) ? lo + (hi - lo) * (double)(fl + 1) * (1.0 / 65.0) : hi;
            lo = nlo; hi = nhi;
          }
          if (lane == 0) sc[1] = 0.5 * (lo + hi);
        }
        __syncthreads();
        if (tid == 0) {
          const double lam = sc[1];
          for (int i = 0; i < m; ++i) t4[i] = 1.0;
          for (int it = 0; it < 3; ++it) {
            for (int i = 0; i < m; ++i) {
              t1[i] = al[i] - lam;
              t2[i] = (i < m - 1) ? be[i + 1] : 0.0;
              t3[i] = 0.0;
            }
            for (int i = 0; i < m - 1; ++i) {
              double sub = be[i + 1];
              if (fabs(t1[i]) >= fabs(sub)) {
                double piv = t1[i];
                if (fabs(piv) < 1e-300) piv = (piv < 0.0 ? -1e-300 : 1e-300);
                double m1 = sub / piv;
                t1[i] = piv;
                t1[i + 1] -= m1 * t2[i];
                t4[i + 1] -= m1 * t4[i];
              } else {
                double m1 = t1[i] / sub;
                double od = t1[i + 1], oe = t2[i + 1];
                t1[i] = sub;
                double nd = t2[i] - m1 * od;
                double ne = -m1 * oe;
                t2[i] = od; t3[i] = oe;
                t1[i + 1] = nd; t2[i + 1] = ne;
                double tt = t4[i]; t4[i] = t4[i + 1]; t4[i + 1] = tt - m1 * t4[i];
              }
            }
            {
              double piv = t1[m - 1];
              if (fabs(piv) < 1e-300) piv = (piv < 0.0 ? -1e-300 : 1e-300);
              t4[m - 1] /= piv;
            }
            if (m >= 2) {
              double piv = t1[m - 2];
              if (fabs(piv) < 1e-300) piv = (piv < 0.0 ? -1e-300 : 1e-300);
              t4[m - 2] = (t4[m - 2] - t2[m - 2] * t4[m - 1]) / piv;
            }
            for (int i = m - 3; i >= 0; --i) {
              double piv = t1[i];
              if (fabs(piv) < 1e-300) piv = (piv < 0.0 ? -1e-300 : 1e-300);
              t4[i] = (t4[i] - t2[i] * t4[i + 1] - t3[i] * t4[i + 2]) / piv;
            }
            double s = 0.0;
            for (int i = 0; i < m; ++i) s += t4[i] * t4[i];
            double isn = 1.0 / sqrt(s);
            for (int i = 0; i < m; ++i) t4[i] *= isn;
          }
          for (int i = 0; i < m; ++i) yv[i] = t4[i];
          sc[2] = be[m] * fabs(t4[m - 1]);  // Ritz residual
        }
        __syncthreads();
        lastResid = sc[2];
        if (lastResid < TOL) conv = true;
        if (conv || m == mcap) break;
      }
      if (r < N) {
        double nz = ww[r] / bnew;
        vp[r] = zs[r];
        zs[r] = nz;
        Vb[(size_t)m * N + r] = nz;
      }
      __syncthreads();
    }
    mfin = m;

    // u = V y  -> ww
    __syncthreads();
    {
      const int rr = wv * 49 + lane;
      if (lane < 49) {
        double acc = 0.0;
        for (int j = 0; j < mfin; ++j) acc += yv[j] * Vb[(size_t)j * N + rr];
        ww[rr] = acc;
      }
    }
    __syncthreads();
    if (conv || totm >= BUDGET) break;
    double cu2 = bsum((r < N) ? ww[r] * u0s[r] : 0.0, red);
    if (r < N) ww[r] -= cu2 * u0s[r];
    double nr2 = sqrt(bsum((r < N) ? ww[r] * ww[r] : 0.0, red));
    if (r < N) zs[r] = ww[r] / nr2;
    __syncthreads();
  }

  // epilogue from ww (= u, unnormalized)
  double un = bsum((r < N) ? ww[r] * ww[r] : 0.0, red);
  double uinv = 1.0 / sqrt(un);
  if (r < N) zs[r] = ww[r] * uinv * qs[r];  // v = u * d^{-1/2}
  double sv = bsum((r < N) ? zs[r] : 0.0, red);
  double avg = sv * (1.0 / 784.0);
  double e = -1.0;
  if (r < N) {
    double v = zs[r];
    bool s = (avg > 0.0) ? (v > 0.0) : (v <= 0.0);
    e = s ? fabs(v) : -1.0;
    if (e == 0.0) e = -1.0;
  }
  double mx = bmax(e, red);
  double ez = (e >= 0.0) ? exp(e - mx) : 0.0;
  double Z = bsum(ez, red);
  if (r < N) out[(size_t)b * N + r] = (float)(ez / Z);

  // diagnostics: ONLY on non-convergence
  if (tid == 0 && !conv) {
    double diag;
    if (mcap < 64) {
      diag = 1.0e6 + (double)wsMB;
    } else {
      double lr = fmax(lastResid, 1e-30);
      double ex = floor(log10(lr) + 30.0);
      ex = fmax(0.0, fmin(99.0, ex));
      diag = 1.0e8 + ex * 1.0e6 + (double)totm * 10.0;
    }
    out[(size_t)b * N] = (float)diag;
  }
}

// ---------------- host ----------------
extern "C" void kernel_launch(void* const* d_in, const int* in_sizes, int n_in,
                              void* d_out, int out_size, void* d_ws, size_t ws_size,
                              hipStream_t stream) {
  const float* k1 = (const float*)d_in[0];
  const float* k2 = (const float*)d_in[1];
  float* out = (float*)d_out;
  char* ws = (char*)d_ws;
  size_t off = 0;
  auto carve = [&](size_t bytes) {
    void* p = ws + off;
    off += (bytes + 255) & ~(size_t)255;
    return p;
  };
  unsigned long long* mask = (unsigned long long*)carve((size_t)NB * NW * N * 8);
  double* q = (double*)carve((size_t)NB * N * 8);
  double* u0 = (double*)carve((size_t)NB * N * 8);
  size_t rem = (ws_size > off) ? (ws_size - off) : 0;
  int mcap = (int)((rem / 8) / ((size_t)NB * N));
  if (mcap > MMAX) mcap = MMAX;
  if (mcap < 8) mcap = 8;
  double* V = (double*)carve((size_t)NB * mcap * N * 8);
  int wsMB = (int)(ws_size >> 20);

  k_gram_np<<<dim3(13, 13, NB), dim3(256), 0, stream>>>(k1, k2, mask);
  k_stats<<<dim3(NB), dim3(256), 0, stream>>>(mask, q, u0);
  k_lanczos<<<dim3(NB), dim3(1024), 0, stream>>>(mask, q, u0, V, out, mcap, wsMB);
}

// Round 6
// 3773.034 us; speedup vs baseline: 1.3587x; 1.3587x over previous
//
#include <hip/hip_runtime.h>

// Spatial_Weighting: per (b,t): feats = K1 K1^T + K2 K2^T (784x784, K=768),
// W=(feats>0.2)?1:1e-5, normalized-Laplacian Fiedler vector, bipartition softmax.
// Mask from bit-exact numpy-f32-einsum emulation (SSE 4-lane acc, no FMA);
// solve via f64 restarted Lanczos. R6: symmetric Gram tiles (exact), 64-K LDS
// staging, 4-bit matvec table, fused 2-value reductions, stats fused.

constexpr int NB = 32;        // B*T batches
constexpr int N  = 784;       // nodes
constexpr int H  = 12, Dd = 64;
constexpr int NW = 13;        // u64 words per row (832 bits, 784 used)
constexpr int MMAX = 384;     // Lanczos basis cap per cycle (multiple of 16)
constexpr double WA = 1e-5;
constexpr double WB = 1.0 - 1e-5;
constexpr double TOL = 1e-10;
constexpr int BUDGET = 1536;

// ---- Kernel 1: symmetric-tile f32-einsum Gram -> bitmask ----
__global__ __launch_bounds__(256)
void k_gram_np(const float* __restrict__ k1, const float* __restrict__ k2,
               unsigned long long* __restrict__ mask) {
  // triangular tile decode: t -> (by, bx), bx >= by
  int rem = blockIdx.x, by = 0;
  while (rem >= 13 - by) { rem -= 13 - by; ++by; }
  const int bx = by + rem;
  const int b = blockIdx.y;
  const int n0 = by * 64, m0 = bx * 64;
  const int tx = threadIdx.x & 15, ty = threadIdx.x >> 4;

  __shared__ float As[64][68];
  __shared__ float Bs[64][68];
  __shared__ unsigned int mw[64][2];
  __shared__ unsigned int mw2[64][2];

  float e01[2][4][4];
  const float* keys[2] = {k1 + (size_t)b * H * N * Dd, k2 + (size_t)b * H * N * Dd};

  for (int ki = 0; ki < 2; ++ki) {
    float acc[4][4][4];
#pragma unroll
    for (int i = 0; i < 4; ++i)
#pragma unroll
      for (int j = 0; j < 4; ++j)
#pragma unroll
        for (int L = 0; L < 4; ++L) acc[i][j][L] = 0.0f;

    const float* K = keys[ki];
    for (int h = 0; h < H; ++h) {
      const float* Kh = K + (size_t)h * N * Dd;
      __syncthreads();
      // stage full 64-wide K chunk (one head) for both row sets
#pragma unroll
      for (int s = 0; s < 4; ++s) {
        int f = s * 256 + threadIdx.x;       // 1024 float4 slots
        int row = f >> 4, c4 = (f & 15) * 4;
        int gr = n0 + row; gr = gr < N ? gr : N - 1;
        *(float4*)&As[row][c4] = *(const float4*)(Kh + (size_t)gr * Dd + c4);
        int gr2 = m0 + row; gr2 = gr2 < N ? gr2 : N - 1;
        *(float4*)&Bs[row][c4] = *(const float4*)(Kh + (size_t)gr2 * Dd + c4);
      }
      __syncthreads();
      // EXACT numpy f32 SSE order: acc[L] = fadd(acc[L], fmul(a,b)), c = kb*4+L
#pragma unroll 4
      for (int kb = 0; kb < 16; ++kb) {
        float4 av[4], bv[4];
#pragma unroll
        for (int i = 0; i < 4; ++i) av[i] = *(const float4*)&As[ty * 4 + i][kb * 4];
#pragma unroll
        for (int j = 0; j < 4; ++j) bv[j] = *(const float4*)&Bs[tx * 4 + j][kb * 4];
#pragma unroll
        for (int i = 0; i < 4; ++i)
#pragma unroll
          for (int j = 0; j < 4; ++j) {
            acc[i][j][0] = __fadd_rn(acc[i][j][0], __fmul_rn(av[i].x, bv[j].x));
            acc[i][j][1] = __fadd_rn(acc[i][j][1], __fmul_rn(av[i].y, bv[j].y));
            acc[i][j][2] = __fadd_rn(acc[i][j][2], __fmul_rn(av[i].z, bv[j].z));
            acc[i][j][3] = __fadd_rn(acc[i][j][3], __fmul_rn(av[i].w, bv[j].w));
          }
      }
    }
    // EINSUM_SUM_SSE horizontal: (s0+s2)+(s1+s3)
#pragma unroll
    for (int i = 0; i < 4; ++i)
#pragma unroll
      for (int j = 0; j < 4; ++j)
        e01[ki][i][j] = __fadd_rn(__fadd_rn(acc[i][j][0], acc[i][j][2]),
                                  __fadd_rn(acc[i][j][1], acc[i][j][3]));
  }

  __syncthreads();
  if (threadIdx.x < 128) {
    ((unsigned int*)mw)[threadIdx.x] = 0u;
    ((unsigned int*)mw2)[threadIdx.x] = 0u;
  }
  __syncthreads();
  unsigned int nt[4] = {0u, 0u, 0u, 0u};
#pragma unroll
  for (int i = 0; i < 4; ++i) {
    unsigned int nn = 0;
    const bool n_ok = (n0 + ty * 4 + i) < N;
#pragma unroll
    for (int j = 0; j < 4; ++j) {
      int m = m0 + tx * 4 + j;
      float feats = __fadd_rn(e01[0][i][j], e01[1][i][j]);
      bool on = feats > 0.2f;
      if (m < N && on) nn |= (1u << j);
      if (n_ok && on) nt[j] |= (1u << i);
    }
    atomicOr(&mw[ty * 4 + i][tx >> 3], nn << ((tx & 7) * 4));
  }
#pragma unroll
  for (int j = 0; j < 4; ++j)
    atomicOr(&mw2[tx * 4 + j][ty >> 3], nt[j] << ((ty & 7) * 4));
  __syncthreads();
  if (threadIdx.x < 64) {
    int n = n0 + threadIdx.x;
    if (n < N) {
      unsigned long long w =
          ((unsigned long long)mw[threadIdx.x][1] << 32) | (unsigned long long)mw[threadIdx.x][0];
      mask[((size_t)b * NW + bx) * N + n] = w;
    }
    if (bx != by) {   // mirrored tile (feats symmetric bit-exactly)
      int m = m0 + threadIdx.x;
      if (m < N) {
        unsigned long long w =
            ((unsigned long long)mw2[threadIdx.x][1] << 32) | (unsigned long long)mw2[threadIdx.x][0];
        mask[((size_t)b * NW + by) * N + m] = w;
      }
    }
  }
}

// ---------------- helpers ----------------
__device__ __forceinline__ double rnd01(unsigned long long x) {
  x += 0x9E3779B97F4A7C15ull;
  x = (x ^ (x >> 30)) * 0xBF58476D1CE4E5B9ull;
  x = (x ^ (x >> 27)) * 0x94D049BB133111EBull;
  x ^= x >> 31;
  return (double)(x >> 11) * (1.0 / 9007199254740992.0) - 0.5;
}

// two-value block reduction, 2 barriers; results in sc2[0], sc2[1]
__device__ __forceinline__ void bsum2(double a, double c, double* red, double* sc2) {
  const int tid = threadIdx.x, lane = tid & 63, wv = tid >> 6;
#pragma unroll
  for (int o = 32; o; o >>= 1) { a += __shfl_down(a, o); c += __shfl_down(c, o); }
  if (lane == 0) { red[wv] = a; red[16 + wv] = c; }
  __syncthreads();
  if (tid < 64) {
    double x = (lane < 16) ? red[lane] : 0.0;
    double y = (lane < 16) ? red[16 + lane] : 0.0;
#pragma unroll
    for (int o = 8; o; o >>= 1) { x += __shfl_down(x, o); y += __shfl_down(y, o); }
    if (lane == 0) { sc2[0] = x; sc2[1] = y; }
  }
  __syncthreads();
}

__device__ __forceinline__ double bmax(double v, double* red) {
  const int tid = threadIdx.x;
  __syncthreads();
#pragma unroll
  for (int o = 32; o; o >>= 1) v = fmax(v, __shfl_down(v, o));
  if ((tid & 63) == 0) red[tid >> 6] = v;
  __syncthreads();
  if (tid < 64) {
    double x = (tid < 16) ? red[tid] : -1e300;
#pragma unroll
    for (int o = 8; o; o >>= 1) x = fmax(x, __shfl_down(x, o));
    if (tid == 0) red[0] = x;
  }
  __syncthreads();
  return red[0];
}

__device__ int cntless(const double* al, const double* be, int m, double x) {
  double d = al[0] - x;
  int c = (d < 0.0);
  for (int i = 1; i < m; ++i) {
    double den = d;
    if (fabs(den) < 1e-300) den = (den < 0.0 ? -1e-300 : 1e-300);
    d = al[i] - x - be[i] * be[i] / den;
    c += (d < 0.0);
  }
  return c;
}

// CGS2 full reorth of ww (LDS, length N) against V[0..k] (global)
__device__ void cgs2(double* ww, const double* Vb, int k, double* cd) {
  const int tid = threadIdx.x, wv = tid >> 6, lane = tid & 63;
  for (int round = 0; round < 2; ++round) {
    __syncthreads();
    for (int j = wv; j <= k; j += 16) {
      const double* Vj = Vb + (size_t)j * N;
      double p = 0.0;
      for (int c = lane; c < N; c += 64) p += ww[c] * Vj[c];
#pragma unroll
      for (int o = 32; o; o >>= 1) p += __shfl_down(p, o);
      if (lane == 0) cd[j] = p;
    }
    __syncthreads();
    const int rr = wv * 49 + lane;   // 16*49 = 784
    if (lane < 49) {
      double acc = ww[rr];
      for (int j = 0; j <= k; ++j) acc -= cd[j] * Vb[(size_t)j * N + rr];
      ww[rr] = acc;
    }
    __syncthreads();
  }
}

// ---------------- Kernel 2: persistent per-batch restarted Lanczos ---------
__global__ __launch_bounds__(1024)
void k_lanczos(const unsigned long long* __restrict__ mask,
               double* __restrict__ V, float* __restrict__ out, int mcap, int wsMB) {
  const int b = blockIdx.x;
  const int tid = threadIdx.x;
  const int lane = tid & 63, wv = tid >> 6;
  const int r = tid;  // row (active when r < N)

  __shared__ double zs[N], ww[N], vp[N], u0s[N], qs[N], tz[N];
  __shared__ double tbl[208 * 16];                 // 4-bit lookup table
  __shared__ double al[MMAX + 1], be[MMAX + 2], yv[MMAX + 1];
  __shared__ double t1[MMAX + 1], t2[MMAX + 1], t3[MMAX + 1], t4[MMAX + 1];
  __shared__ double red[32];
  __shared__ double sc[8];

  const unsigned long long* mrow = mask + (size_t)b * NW * N;
  double* Vb = V + (size_t)b * mcap * N;

  // ---- fused stats: degrees -> qs, u0s (bit-identical math to old k_stats) ----
  unsigned long long wbits[NW];
  double dloc = 0.0;
  if (r < N) {
#pragma unroll
    for (int w = 0; w < NW; ++w) wbits[w] = mrow[(size_t)w * N + r];
    int c = 0;
#pragma unroll
    for (int w = 0; w < NW; ++w) c += __popcll(wbits[w]);
    double d = (double)c * WB + (double)N * WA;
    qs[r] = 1.0 / sqrt(d);
    u0s[r] = sqrt(d);
    dloc = d;
    zs[r] = rnd01((unsigned long long)(b * 100003 + r));
  }
  bsum2(dloc, 0.0, red, sc);
  {
    double invS = 1.0 / sqrt(sc[0]);
    if (r < N) u0s[r] *= invS;
  }
  // project out exact top eigvec u0, normalize
  bsum2((r < N) ? zs[r] * u0s[r] : 0.0, 0.0, red, sc);
  if (r < N) zs[r] -= sc[0] * u0s[r];
  bsum2((r < N) ? zs[r] * zs[r] : 0.0, 0.0, red, sc);
  {
    double nr = sqrt(sc[0]);
    if (r < N) zs[r] /= nr;
  }

  bool conv = false;
  int totm = 0, mfin = 0;
  double lastResid = 1e30;

  for (int cyc = 0; cyc < 16; ++cyc) {
    if (r < N) { Vb[r] = zs[r]; vp[r] = 0.0; ww[r] = zs[r]; }
    if (tid == 0) be[0] = 0.0;
    double bprev = 1.0;
    bsum2((r < N) ? qs[r] * zs[r] : 0.0, 0.0, red, sc);
    double s1 = sc[0];

    int m = 0;
    for (int k = 0; k < mcap; ++k) {
      __syncthreads();
      // phase 1: rotate (k>0) + tz = q .* z_k
      if (k > 0 && r < N) {
        double nz = ww[r] / bprev;
        vp[r] = zs[r];
        zs[r] = nz;
        Vb[(size_t)k * N + r] = nz;
      }
      if (r < N) tz[r] = qs[r] * zs[r];
      __syncthreads();
      // 4-bit table build: tbl[g*16+mask4] = sum of selected tz[g*4..g*4+3]
      for (int e = tid; e < 208 * 16; e += 1024) {
        int g = e >> 4, mm = e & 15, x0 = g << 2;
        double s = 0.0;
        if (x0 < N) {
          if (mm & 1) s += tz[x0];
          if (mm & 2) s += tz[x0 + 1];
          if (mm & 4) s += tz[x0 + 2];
          if (mm & 8) s += tz[x0 + 3];
        }
        tbl[e] = s;
      }
      __syncthreads();
      // matvec: w = q .* (WB * gather + WA * s1)
      if (r < N) {
        double a0 = 0.0, a1 = 0.0;
#pragma unroll
        for (int w = 0; w < NW; ++w) {
          unsigned long long bits = wbits[w];
          const double* tb = &tbl[w << 8];
#pragma unroll
          for (int p = 0; p < 16; p += 2) {
            a0 += tb[(p << 4) + (int)(bits & 15ull)];
            a1 += tb[((p + 1) << 4) + (int)((bits >> 4) & 15ull)];
            bits >>= 8;
          }
        }
        ww[r] = qs[r] * (WB * (a0 + a1) + WA * s1);
      }
      ++totm;
      // pass A: alpha = <w,z>, cu0 = <w,u0> (deflation first-order exact:
      // <z,u0>,<v,u0> ~ 1e-16 from explicit per-step deflation)
      bsum2((r < N) ? ww[r] * zs[r] : 0.0, (r < N) ? ww[r] * u0s[r] : 0.0, red, sc);
      double alpha = sc[0], cu0 = sc[1];
      if (r < N) ww[r] -= alpha * zs[r] + bprev * vp[r] + cu0 * u0s[r];

      m = k + 1;
      if (((m & 15) == 0) || (m == mcap)) cgs2(ww, Vb, k, yv);

      // pass B: nn = <w',w'>, sq = <w',q>  -> bnew, next s1
      bsum2((r < N) ? ww[r] * ww[r] : 0.0, (r < N) ? ww[r] * qs[r] : 0.0, red, sc);
      double bnew = sqrt(sc[0]);
      s1 = sc[1] / bnew;
      if (tid == 0) { al[k] = alpha; be[m] = bnew; }
      bprev = bnew;

      const bool doCheck = (((m & 15) == 0) && m >= 32) || (m == mcap);
      if (doCheck) {
        __syncthreads();   // al/be visible to all
        double gmax = bmax((tid < m) ? al[tid] + (tid > 0 ? be[tid] : 0.0) +
                                           (tid < m - 1 ? be[tid + 1] : 0.0)
                                     : -1e300, red);
        double dmax = bmax((tid < m) ? al[tid] : -1e300, red);
        if (tid < 64) {
          double lo = dmax, hi = gmax + 1e-9;
          for (int round = 0; round < 4; ++round) {
            double xl = lo + (hi - lo) * (double)(lane + 1) * (1.0 / 65.0);
            int c = cntless(al, be, m, xl);
            unsigned long long mk = __ballot(c >= m);
            int fl = (mk == 0ull) ? 64 : (__ffsll(mk) - 1);
            double nlo = lo + (hi - lo) * (double)fl * (1.0 / 65.0);
            double nhi = (fl < 64) ? lo + (hi - lo) * (double)(fl + 1) * (1.0 / 65.0) : hi;
            lo = nlo; hi = nhi;
          }
          if (lane == 0) sc[4] = 0.5 * (lo + hi);
        }
        __syncthreads();
        if (tid == 0) {
          const double lam = sc[4];
          for (int i = 0; i < m; ++i) t4[i] = 1.0;
          for (int it = 0; it < 3; ++it) {
            for (int i = 0; i < m; ++i) {
              t1[i] = al[i] - lam;
              t2[i] = (i < m - 1) ? be[i + 1] : 0.0;
              t3[i] = 0.0;
            }
            for (int i = 0; i < m - 1; ++i) {
              double sub = be[i + 1];
              if (fabs(t1[i]) >= fabs(sub)) {
                double piv = t1[i];
                if (fabs(piv) < 1e-300) piv = (piv < 0.0 ? -1e-300 : 1e-300);
                double m1 = sub / piv;
                t1[i] = piv;
                t1[i + 1] -= m1 * t2[i];
                t4[i + 1] -= m1 * t4[i];
              } else {
                double m1 = t1[i] / sub;
                double od = t1[i + 1], oe = t2[i + 1];
                t1[i] = sub;
                double nd = t2[i] - m1 * od;
                double ne = -m1 * oe;
                t2[i] = od; t3[i] = oe;
                t1[i + 1] = nd; t2[i + 1] = ne;
                double tt = t4[i]; t4[i] = t4[i + 1]; t4[i + 1] = tt - m1 * t4[i];
              }
            }
            {
              double piv = t1[m - 1];
              if (fabs(piv) < 1e-300) piv = (piv < 0.0 ? -1e-300 : 1e-300);
              t4[m - 1] /= piv;
            }
            if (m >= 2) {
              double piv = t1[m - 2];
              if (fabs(piv) < 1e-300) piv = (piv < 0.0 ? -1e-300 : 1e-300);
              t4[m - 2] = (t4[m - 2] - t2[m - 2] * t4[m - 1]) / piv;
            }
            for (int i = m - 3; i >= 0; --i) {
              double piv = t1[i];
              if (fabs(piv) < 1e-300) piv = (piv < 0.0 ? -1e-300 : 1e-300);
              t4[i] = (t4[i] - t2[i] * t4[i + 1] - t3[i] * t4[i + 2]) / piv;
            }
            double s = 0.0;
            for (int i = 0; i < m; ++i) s += t4[i] * t4[i];
            double isn = 1.0 / sqrt(s);
            for (int i = 0; i < m; ++i) t4[i] *= isn;
          }
          for (int i = 0; i < m; ++i) yv[i] = t4[i];
          sc[5] = be[m] * fabs(t4[m - 1]);  // Ritz residual
        }
        __syncthreads();
        lastResid = sc[5];
        if (lastResid < TOL) conv = true;
        if (conv || m == mcap) break;
      }
    }
    mfin = m;

    // u = V y  -> ww
    __syncthreads();
    {
      const int rr = wv * 49 + lane;
      if (lane < 49) {
        double acc = 0.0;
        for (int j = 0; j < mfin; ++j) acc += yv[j] * Vb[(size_t)j * N + rr];
        ww[rr] = acc;
      }
    }
    __syncthreads();
    if (conv || totm >= BUDGET) break;
    // restart from Ritz vector: deflate u0, normalize -> zs
    bsum2((r < N) ? ww[r] * u0s[r] : 0.0, 0.0, red, sc);
    if (r < N) ww[r] -= sc[0] * u0s[r];
    bsum2((r < N) ? ww[r] * ww[r] : 0.0, 0.0, red, sc);
    {
      double nr2 = sqrt(sc[0]);
      if (r < N) zs[r] = ww[r] / nr2;
    }
    __syncthreads();
  }

  // epilogue from ww (= u, unnormalized)
  bsum2((r < N) ? ww[r] * ww[r] : 0.0, 0.0, red, sc);
  double uinv = 1.0 / sqrt(sc[0]);
  if (r < N) zs[r] = ww[r] * uinv * qs[r];  // v = u * d^{-1/2}
  bsum2((r < N) ? zs[r] : 0.0, 0.0, red, sc);
  double avg = sc[0] * (1.0 / 784.0);
  double e = -1.0;
  if (r < N) {
    double v = zs[r];
    bool s = (avg > 0.0) ? (v > 0.0) : (v <= 0.0);
    e = s ? fabs(v) : -1.0;
    if (e == 0.0) e = -1.0;  // reference maps e==0 -> -inf
  }
  double mx = bmax(e, red);
  double ez = (e >= 0.0) ? exp(e - mx) : 0.0;
  bsum2(ez, 0.0, red, sc);
  double Z = sc[0];
  if (r < N) out[(size_t)b * N + r] = (float)(ez / Z);

  // diagnostics: ONLY on non-convergence
  if (tid == 0 && !conv) {
    double diag;
    if (mcap < 64) {
      diag = 1.0e6 + (double)wsMB;
    } else {
      double lr = fmax(lastResid, 1e-30);
      double ex = floor(log10(lr) + 30.0);
      ex = fmax(0.0, fmin(99.0, ex));
      diag = 1.0e8 + ex * 1.0e6 + (double)totm * 10.0;
    }
    out[(size_t)b * N] = (float)diag;
  }
}

// ---------------- host ----------------
extern "C" void kernel_launch(void* const* d_in, const int* in_sizes, int n_in,
                              void* d_out, int out_size, void* d_ws, size_t ws_size,
                              hipStream_t stream) {
  const float* k1 = (const float*)d_in[0];
  const float* k2 = (const float*)d_in[1];
  float* out = (float*)d_out;
  char* ws = (char*)d_ws;
  size_t off = 0;
  auto carve = [&](size_t bytes) {
    void* p = ws + off;
    off += (bytes + 255) & ~(size_t)255;
    return p;
  };
  unsigned long long* mask = (unsigned long long*)carve((size_t)NB * NW * N * 8);
  size_t rem = (ws_size > off) ? (ws_size - off) : 0;
  int mcap = (int)((rem / 8) / ((size_t)NB * N));
  if (mcap > MMAX) mcap = MMAX;
  if (mcap < 8) mcap = 8;
  double* V = (double*)carve((size_t)NB * mcap * N * 8);
  int wsMB = (int)(ws_size >> 20);

  k_gram_np<<<dim3(91, NB), dim3(256), 0, stream>>>(k1, k2, mask);
  k_lanczos<<<dim3(NB), dim3(1024), 0, stream>>>(mask, V, out, mcap, wsMB);
}